// Round 4
// baseline (82.339 us; speedup 1.0000x reference)
//
#include <hip/hip_runtime.h>
#include <hip/hip_bf16.h>
#include <stdint.h>

// FullTucker: Z = U0 @ einsum('pqr,qb,rb->pb', G, U1^T@X1, U2^T@X2)
// D_OUT=D1=D2=512, R0=R1=R2=128, BATCH=8192. f32 in/out; bf16 MFMA inside.
// k_core: core[p,b] = sum_q x1[q,b] * (sum_r G[p,q,r]*u2[r,b])
//   All-register main loop: B (UX2T) hoisted 64 VGPR per r-half-pass,
//   A (G) fragments loaded L2->reg directly, x1 folded as f32 fmac.
//   No LDS ops, no barriers until the epilogue transpose.

typedef __attribute__((ext_vector_type(8))) short bf8;   // 8 bf16 (4 VGPR)
typedef __attribute__((ext_vector_type(4))) short bf4;   // 4 bf16 (8B)
typedef __attribute__((ext_vector_type(4))) float f4;    // 4 f32

__device__ __forceinline__ unsigned short f2bf(float f){
  unsigned x = __builtin_bit_cast(unsigned, f);
  x += 0x7fffu + ((x >> 16) & 1u);            // RNE (inputs finite)
  return (unsigned short)(x >> 16);
}
__device__ __forceinline__ float bf2f(unsigned short u){
  unsigned x = ((unsigned)u) << 16;
  return __builtin_bit_cast(float, x);
}
__device__ __forceinline__ void glds16(const void* g, void* l){
  __builtin_amdgcn_global_load_lds(
      (const __attribute__((address_space(1))) void*)g,
      (__attribute__((address_space(3))) void*)l, 16, 0, 0);
}

// ---------------- merged cast kernel ----------------
// blocks [0,2112): G,U0 -> bf16 (f4 vectorized). blocks [2112,2624): U1,U2 -> transposed bf16.
__global__ __launch_bounds__(256) void k_cast(const float* __restrict__ G,
                                              const float* __restrict__ U0,
                                              const float* __restrict__ U1,
                                              const float* __restrict__ U2,
                                              unsigned short* __restrict__ Gbf,
                                              unsigned short* __restrict__ U0bf,
                                              unsigned short* __restrict__ U1T,
                                              unsigned short* __restrict__ U2T){
  const int blk = blockIdx.x;
  if (blk < 2112){
    const int i4 = blk * 256 + threadIdx.x;                // 0..540671
    const int NG4 = 2097152 / 4;
    const float4* src; unsigned short* dst; int j4;
    if (i4 < NG4){ src = (const float4*)G;  dst = Gbf;  j4 = i4; }
    else         { src = (const float4*)U0; dst = U0bf; j4 = i4 - NG4; }
    float4 v = src[j4];
    ushort4 o = make_ushort4(f2bf(v.x), f2bf(v.y), f2bf(v.z), f2bf(v.w));
    ((ushort4*)dst)[j4] = o;
  } else {
    const int b2 = blk - 2112;                             // 0..511
    const float* U = (b2 < 256) ? U1 : U2;
    unsigned short* UT = (b2 < 256) ? U1T : U2T;
    const int idx = (b2 & 255) * 256 + threadIdx.x;        // 0..65535
    const int d = idx >> 7, q = idx & 127;
    UT[q * 512 + d] = f2bf(U[idx]);
  }
}

// ---------------- UX GEMM (both modes, one dispatch) ----------------
// OUT[qr,b] = sum_d UT[qr][d]*X[d][b]. blockIdx.y==0: f32 out; ==1: bf16 transposed.
__global__ __launch_bounds__(256) void k_ux2(const unsigned short* __restrict__ U1T,
                                             const unsigned short* __restrict__ U2T,
                                             const float* __restrict__ X1,
                                             const float* __restrict__ X2,
                                             float* __restrict__ OUTF,
                                             unsigned short* __restrict__ OUTT){
  const bool second = (blockIdx.y != 0);
  const unsigned short* UT = second ? U2T : U1T;
  const float* X = second ? X2 : X1;
  __shared__ __align__(16) unsigned char lds[16384 + 8192];
  unsigned char* ldsA = lds;
  unsigned char* ldsB = lds + 16384;
  const int tid = threadIdx.x, lane = tid & 63, wv = tid >> 6;
  const int wr = wv >> 1, wc = wv & 1;
  const int b0 = blockIdx.x * 64;
  f4 acc[4][2] = {};

  for (int it = 0; it < 8; ++it){
    const int k0 = it * 64;
#pragma unroll
    for (int i = 0; i < 4; ++i){
      const int L = (wv * 4 + i) * 1024 + lane * 16;
      const int row = L >> 7;
      const int ss = (lane & 7) ^ (row & 7);
      glds16(UT + (size_t)row * 512 + k0 + ss * 8, ldsA + (wv * 4 + i) * 1024);
    }
#pragma unroll
    for (int c = 0; c < 2; ++c){
      const int slot = c * 4 + wv;
      const int bRow = lane;
      bf8 v;
#pragma unroll
      for (int j = 0; j < 8; ++j)
        v[j] = (short)f2bf(X[(size_t)(k0 + slot * 8 + j) * 8192 + b0 + bRow]);
      *(bf8*)(ldsB + bRow * 128 + ((slot ^ (bRow & 7)) << 4)) = v;
    }
    __syncthreads();
#pragma unroll
    for (int kc = 0; kc < 2; ++kc){
      const int g = lane >> 4;
      bf8 a[4], b[2];
#pragma unroll
      for (int mf = 0; mf < 4; ++mf){
        const int r = wr * 64 + mf * 16 + (lane & 15);
        a[mf] = *(const bf8*)(ldsA + r * 128 + (((kc * 4 + g) ^ (r & 7)) << 4));
      }
#pragma unroll
      for (int nf = 0; nf < 2; ++nf){
        const int rb = wc * 32 + nf * 16 + (lane & 15);
        b[nf] = *(const bf8*)(ldsB + rb * 128 + (((kc * 4 + g) ^ (rb & 7)) << 4));
      }
#pragma unroll
      for (int mf = 0; mf < 4; ++mf)
#pragma unroll
        for (int nf = 0; nf < 2; ++nf)
          acc[mf][nf] = __builtin_amdgcn_mfma_f32_16x16x32_bf16(a[mf], b[nf], acc[mf][nf], 0, 0, 0);
    }
    __syncthreads();
  }

  if (!second){
#pragma unroll
    for (int mf = 0; mf < 4; ++mf)
#pragma unroll
      for (int nf = 0; nf < 2; ++nf)
#pragma unroll
        for (int j = 0; j < 4; ++j){
          const int q = wr * 64 + mf * 16 + (lane >> 4) * 4 + j;
          const int b = b0 + wc * 32 + nf * 16 + (lane & 15);
          OUTF[(size_t)q * 8192 + b] = acc[mf][nf][j];
        }
  } else {
#pragma unroll
    for (int mf = 0; mf < 4; ++mf)
#pragma unroll
      for (int nf = 0; nf < 2; ++nf){
        const int rBase = wr * 64 + mf * 16 + (lane >> 4) * 4;
        const int bL = wc * 32 + nf * 16 + (lane & 15);
        bf4 p;
#pragma unroll
        for (int j = 0; j < 4; ++j) p[j] = (short)f2bf(acc[mf][nf][j]);
        *(bf4*)(lds + ((bL * 256 + rBase * 2) ^ ((bL & 7) << 4))) = p;
      }
    __syncthreads();
#pragma unroll
    for (int u = 0; u < 4; ++u){
      const int sIdx = u * 256 + tid;
      const int bL = sIdx >> 4, slot = sIdx & 15;
      bf8 v = *(const bf8*)(lds + bL * 256 + ((slot ^ (bL & 7)) << 4));
      *(bf8*)(OUTT + (size_t)(b0 + bL) * 128 + slot * 8) = v;
    }
  }
}

// ---------------- core: all-register per-q GEMM, split-K(q)=4 ----------------
// Block 128p x 128b, 8 waves, wave = 16p x 128b. Two r-half passes share acc.
// No LDS / barriers in main loop; epilogue LDS transpose -> PT[split][b][p].
__global__ __launch_bounds__(512, 2) void k_core(const unsigned short* __restrict__ Gbf,  // [128][16384]
                                                 const float* __restrict__ UX1,           // [128][8192]
                                                 const unsigned short* __restrict__ UX2T, // [8192][128]
                                                 float* __restrict__ PT){                 // [4][8192][128]
  __shared__ __align__(16) unsigned char lds[65536];
  const int tid = threadIdx.x, lane = tid & 63, wv = tid >> 6;
  const int g = lane >> 4, l15 = lane & 15;
  // XCD-aware mapping: round-robin dispatch => xcd = blk & 7. 2 XCDs per split
  // so each XCD's L2 only holds its split's 1 MB G-slice.
  const int blk = blockIdx.x;               // 0..255
  const int xcd = blk & 7, slot = blk >> 3; // slot 0..31
  const int split = xcd >> 1;               // 0..3
  const int bblk = (xcd & 1) * 32 + slot;   // 0..63
  const int b0 = bblk * 128;
  const int q0 = split * 32;
  const int p0 = wv * 16;

  f4 acc[8] = {(f4){0,0,0,0}};
#pragma unroll
  for (int nf = 0; nf < 8; ++nf) acc[nf] = (f4){0.f, 0.f, 0.f, 0.f};

#pragma unroll
  for (int h = 0; h < 2; ++h){
    // hoist B fragments for this r-half: [kc][nf] = 16 x bf8 = 64 VGPR
    bf8 Bf[2][8];
#pragma unroll
    for (int kc = 0; kc < 2; ++kc)
#pragma unroll
      for (int nf = 0; nf < 8; ++nf)
        Bf[kc][nf] = *(const bf8*)(UX2T + (size_t)(b0 + nf * 16 + l15) * 128 +
                                   h * 64 + kc * 32 + g * 8);
    // per-lane A / x1 base pointers
    const unsigned short* ap = Gbf + (size_t)(p0 + l15) * 16384 + q0 * 128 + h * 64 + g * 8;
    const float* xp = UX1 + (size_t)q0 * 8192 + b0 + l15;

    bf8 a0 = *(const bf8*)(ap);
    bf8 a1 = *(const bf8*)(ap + 32);
    float xs[8];
#pragma unroll
    for (int nf = 0; nf < 8; ++nf) xs[nf] = xp[nf * 16];

    for (int i = 0; i < 31; ++i){
      // prefetch q+1
      bf8 n0 = *(const bf8*)(ap + (i + 1) * 128);
      bf8 n1 = *(const bf8*)(ap + (i + 1) * 128 + 32);
      float xn[8];
#pragma unroll
      for (int nf = 0; nf < 8; ++nf) xn[nf] = xp[(size_t)(i + 1) * 8192 + nf * 16];
      // Y = G-slice @ u2  (16 MFMA)
      f4 y[8];
#pragma unroll
      for (int nf = 0; nf < 8; ++nf)
        y[nf] = __builtin_amdgcn_mfma_f32_16x16x32_bf16(a0, Bf[0][nf], (f4){0.f,0.f,0.f,0.f}, 0, 0, 0);
#pragma unroll
      for (int nf = 0; nf < 8; ++nf)
        y[nf] = __builtin_amdgcn_mfma_f32_16x16x32_bf16(a1, Bf[1][nf], y[nf], 0, 0, 0);
      // acc += x1[q,b] * Y   (f32)
#pragma unroll
      for (int nf = 0; nf < 8; ++nf) acc[nf] += y[nf] * xs[nf];
      a0 = n0; a1 = n1;
#pragma unroll
      for (int nf = 0; nf < 8; ++nf) xs[nf] = xn[nf];
    }
    { // last q of this pass
      f4 y[8];
#pragma unroll
      for (int nf = 0; nf < 8; ++nf)
        y[nf] = __builtin_amdgcn_mfma_f32_16x16x32_bf16(a0, Bf[0][nf], (f4){0.f,0.f,0.f,0.f}, 0, 0, 0);
#pragma unroll
      for (int nf = 0; nf < 8; ++nf)
        y[nf] = __builtin_amdgcn_mfma_f32_16x16x32_bf16(a1, Bf[1][nf], y[nf], 0, 0, 0);
#pragma unroll
      for (int nf = 0; nf < 8; ++nf) acc[nf] += y[nf] * xs[nf];
    }
  }

  // epilogue: acc -> PT[split][b][p] via swizzled LDS transpose
  // lane holds acc[nf][j]: p = p0 + g*4 + j, b = b0 + nf*16 + l15
#pragma unroll
  for (int nf = 0; nf < 8; ++nf){
    const int bL = nf * 16 + l15;            // 0..127
    const int pq = wv * 4 + g;               // p-quad 0..31
    *(f4*)(lds + bL * 512 + ((pq ^ (bL & 7)) << 4)) = acc[nf];
  }
  __syncthreads();
#pragma unroll
  for (int rnd = 0; rnd < 8; ++rnd){
    const int idx = rnd * 512 + tid;         // 4096 f4
    const int bL = idx >> 5, sl = idx & 31;
    f4 v = *(const f4*)(lds + bL * 512 + ((sl ^ (bL & 7)) << 4));
    *(f4*)(PT + (size_t)split * 1048576 + (size_t)(b0 + bL) * 128 + sl * 4) = v;
  }
}

// ---------------- reduce split-K partials -> coreT bf16 [8192][128] ----------------
__global__ __launch_bounds__(256) void k_red(const float* __restrict__ PT,
                                             unsigned short* __restrict__ coreT){
  const int i4 = blockIdx.x * 256 + threadIdx.x;           // 0..262143
  const f4* P = (const f4*)PT;
  f4 v = P[i4];
  v += P[262144 + i4];
  v += P[2 * 262144 + i4];
  v += P[3 * 262144 + i4];
  ushort4 o = make_ushort4(f2bf(v[0]), f2bf(v[1]), f2bf(v[2]), f2bf(v[3]));
  ((ushort4*)coreT)[i4] = o;
}

// ---------------- Z = U0 @ core: M=512, N=8192, K=128 ----------------
__global__ __launch_bounds__(256) void k_z(const unsigned short* __restrict__ U0bf,  // [512][128]
                                           const unsigned short* __restrict__ coreT, // [8192][128]
                                           float* __restrict__ Z){                   // [512][8192]
  __shared__ __align__(16) unsigned char lds[32768];
  unsigned char* ldsA = lds;
  unsigned char* ldsB = lds + 16384;
  const int tid = threadIdx.x, lane = tid & 63, wv = tid >> 6;
  const int wr = wv >> 1, wc = wv & 1;
  const int b0 = blockIdx.x * 128;
  const int d0 = blockIdx.y * 128;
  f4 acc[4][4] = {};

#pragma unroll
  for (int it = 0; it < 2; ++it){
    const int k0 = it * 64;
#pragma unroll
    for (int i = 0; i < 4; ++i){
      const int L = (wv * 4 + i) * 1024 + lane * 16;
      const int row = L >> 7;
      const int ss = (lane & 7) ^ (row & 7);
      glds16(U0bf + (size_t)(d0 + row) * 128 + k0 + ss * 8, ldsA + (wv * 4 + i) * 1024);
      glds16(coreT + (size_t)(b0 + row) * 128 + k0 + ss * 8, ldsB + (wv * 4 + i) * 1024);
    }
    __syncthreads();
#pragma unroll
    for (int kc = 0; kc < 2; ++kc){
      const int g = lane >> 4;
      bf8 a[4], b[4];
#pragma unroll
      for (int mf = 0; mf < 4; ++mf){
        const int r = wr * 64 + mf * 16 + (lane & 15);
        a[mf] = *(const bf8*)(ldsA + r * 128 + (((kc * 4 + g) ^ (r & 7)) << 4));
      }
#pragma unroll
      for (int nf = 0; nf < 4; ++nf){
        const int rb = wc * 64 + nf * 16 + (lane & 15);
        b[nf] = *(const bf8*)(ldsB + rb * 128 + (((kc * 4 + g) ^ (rb & 7)) << 4));
      }
#pragma unroll
      for (int mf = 0; mf < 4; ++mf)
#pragma unroll
        for (int nf = 0; nf < 4; ++nf)
          acc[mf][nf] = __builtin_amdgcn_mfma_f32_16x16x32_bf16(a[mf], b[nf], acc[mf][nf], 0, 0, 0);
    }
    __syncthreads();
  }
#pragma unroll
  for (int mf = 0; mf < 4; ++mf)
#pragma unroll
    for (int nf = 0; nf < 4; ++nf)
#pragma unroll
      for (int j = 0; j < 4; ++j){
        const int d = d0 + wr * 64 + mf * 16 + (lane >> 4) * 4 + j;
        const int b = b0 + wc * 64 + nf * 16 + (lane & 15);
        Z[(size_t)d * 8192 + b] = acc[mf][nf][j];
      }
}

// ---------------- host launch ----------------
extern "C" void kernel_launch(void* const* d_in, const int* in_sizes, int n_in,
                              void* d_out, int out_size, void* d_ws, size_t ws_size,
                              hipStream_t stream){
  const float* X1 = (const float*)d_in[0];
  const float* X2 = (const float*)d_in[1];
  const float* U0 = (const float*)d_in[2];
  const float* U1 = (const float*)d_in[3];
  const float* U2 = (const float*)d_in[4];
  const float* G  = (const float*)d_in[5];
  float* Z = (float*)d_out;

  char* ws = (char*)d_ws;
  unsigned short* Gbf   = (unsigned short*)(ws);              //  4,194,304 B
  unsigned short* U0bf  = (unsigned short*)(ws + 4194304);    //    131,072 B
  unsigned short* U1T   = (unsigned short*)(ws + 4325376);    //    131,072 B
  unsigned short* U2T   = (unsigned short*)(ws + 4456448);    //    131,072 B
  float*          UX1   = (float*)         (ws + 4587520);    //  4,194,304 B
  unsigned short* UX2T  = (unsigned short*)(ws + 8781824);    //  2,097,152 B
  unsigned short* coreT = (unsigned short*)(ws + 10878976);   //  2,097,152 B
  float*          PT    = (float*)         (ws + 12976128);   // 16,777,216 B

  k_cast<<<dim3(2624), dim3(256), 0, stream>>>(G, U0, U1, U2, Gbf, U0bf, U1T, U2T);
  k_ux2 <<<dim3(128, 2), dim3(256), 0, stream>>>(U1T, U2T, X1, X2, UX1, UX2T);
  k_core<<<dim3(256), dim3(512), 0, stream>>>(Gbf, UX1, UX2T, PT);
  k_red <<<dim3(1024), dim3(256), 0, stream>>>(PT, coreT);
  k_z   <<<dim3(64, 4), dim3(256), 0, stream>>>(U0bf, coreT, Z);
}

// Round 5
// 70.061 us; speedup vs baseline: 1.1753x; 1.1753x over previous
//
#include <hip/hip_runtime.h>
#include <hip/hip_bf16.h>
#include <stdint.h>

// FullTucker: Z = U0 @ einsum('pqr,qb,rb->pb', G, U1^T@X1, U2^T@X2)
// D_OUT=D1=D2=512, R0=R1=R2=128, BATCH=8192. f32 in/out; bf16 MFMA inside.
// k_core: core[p,b] = sum_q x1[q,b] * (sum_r G[p,q,r]*u2[r,b])
//   A (G q-slices) staged via global_load_lds into a 4-deep LDS ring with
//   COUNTED s_waitcnt vmcnt(8) + raw s_barrier (no drain-0 per iter).
//   B (UX2T) hoisted in 64 VGPR for the whole kernel; x1 staged once in LDS;
//   x1 folded post-MFMA as f32 fmac. Wave tile 32p x 64b.

typedef __attribute__((ext_vector_type(8))) short bf8;   // 8 bf16 (4 VGPR)
typedef __attribute__((ext_vector_type(4))) short bf4;   // 4 bf16 (8B)
typedef __attribute__((ext_vector_type(4))) float f4;    // 4 f32

__device__ __forceinline__ unsigned short f2bf(float f){
  unsigned x = __builtin_bit_cast(unsigned, f);
  x += 0x7fffu + ((x >> 16) & 1u);            // RNE (inputs finite)
  return (unsigned short)(x >> 16);
}
__device__ __forceinline__ float bf2f(unsigned short u){
  unsigned x = ((unsigned)u) << 16;
  return __builtin_bit_cast(float, x);
}
__device__ __forceinline__ void glds16(const void* g, void* l){
  __builtin_amdgcn_global_load_lds(
      (const __attribute__((address_space(1))) void*)g,
      (__attribute__((address_space(3))) void*)l, 16, 0, 0);
}

// ---------------- merged cast kernel ----------------
__global__ __launch_bounds__(256) void k_cast(const float* __restrict__ G,
                                              const float* __restrict__ U0,
                                              const float* __restrict__ U1,
                                              const float* __restrict__ U2,
                                              unsigned short* __restrict__ Gbf,
                                              unsigned short* __restrict__ U0bf,
                                              unsigned short* __restrict__ U1T,
                                              unsigned short* __restrict__ U2T){
  const int blk = blockIdx.x;
  if (blk < 2112){
    const int i4 = blk * 256 + threadIdx.x;                // 0..540671
    const int NG4 = 2097152 / 4;
    const float4* src; unsigned short* dst; int j4;
    if (i4 < NG4){ src = (const float4*)G;  dst = Gbf;  j4 = i4; }
    else         { src = (const float4*)U0; dst = U0bf; j4 = i4 - NG4; }
    float4 v = src[j4];
    ushort4 o = make_ushort4(f2bf(v.x), f2bf(v.y), f2bf(v.z), f2bf(v.w));
    ((ushort4*)dst)[j4] = o;
  } else {
    const int b2 = blk - 2112;                             // 0..511
    const float* U = (b2 < 256) ? U1 : U2;
    unsigned short* UT = (b2 < 256) ? U1T : U2T;
    const int idx = (b2 & 255) * 256 + threadIdx.x;        // 0..65535
    const int d = idx >> 7, q = idx & 127;
    UT[q * 512 + d] = f2bf(U[idx]);
  }
}

// ---------------- UX GEMM (both modes, one dispatch) ----------------
__global__ __launch_bounds__(256) void k_ux2(const unsigned short* __restrict__ U1T,
                                             const unsigned short* __restrict__ U2T,
                                             const float* __restrict__ X1,
                                             const float* __restrict__ X2,
                                             float* __restrict__ OUTF,
                                             unsigned short* __restrict__ OUTT){
  const bool second = (blockIdx.y != 0);
  const unsigned short* UT = second ? U2T : U1T;
  const float* X = second ? X2 : X1;
  __shared__ __align__(16) unsigned char lds[16384 + 8192];
  unsigned char* ldsA = lds;
  unsigned char* ldsB = lds + 16384;
  const int tid = threadIdx.x, lane = tid & 63, wv = tid >> 6;
  const int wr = wv >> 1, wc = wv & 1;
  const int b0 = blockIdx.x * 64;
  f4 acc[4][2] = {};

  for (int it = 0; it < 8; ++it){
    const int k0 = it * 64;
#pragma unroll
    for (int i = 0; i < 4; ++i){
      const int L = (wv * 4 + i) * 1024 + lane * 16;
      const int row = L >> 7;
      const int ss = (lane & 7) ^ (row & 7);
      glds16(UT + (size_t)row * 512 + k0 + ss * 8, ldsA + (wv * 4 + i) * 1024);
    }
#pragma unroll
    for (int c = 0; c < 2; ++c){
      const int slot = c * 4 + wv;
      const int bRow = lane;
      bf8 v;
#pragma unroll
      for (int j = 0; j < 8; ++j)
        v[j] = (short)f2bf(X[(size_t)(k0 + slot * 8 + j) * 8192 + b0 + bRow]);
      *(bf8*)(ldsB + bRow * 128 + ((slot ^ (bRow & 7)) << 4)) = v;
    }
    __syncthreads();
#pragma unroll
    for (int kc = 0; kc < 2; ++kc){
      const int g = lane >> 4;
      bf8 a[4], b[2];
#pragma unroll
      for (int mf = 0; mf < 4; ++mf){
        const int r = wr * 64 + mf * 16 + (lane & 15);
        a[mf] = *(const bf8*)(ldsA + r * 128 + (((kc * 4 + g) ^ (r & 7)) << 4));
      }
#pragma unroll
      for (int nf = 0; nf < 2; ++nf){
        const int rb = wc * 32 + nf * 16 + (lane & 15);
        b[nf] = *(const bf8*)(ldsB + rb * 128 + (((kc * 4 + g) ^ (rb & 7)) << 4));
      }
#pragma unroll
      for (int mf = 0; mf < 4; ++mf)
#pragma unroll
        for (int nf = 0; nf < 2; ++nf)
          acc[mf][nf] = __builtin_amdgcn_mfma_f32_16x16x32_bf16(a[mf], b[nf], acc[mf][nf], 0, 0, 0);
    }
    __syncthreads();
  }

  if (!second){
#pragma unroll
    for (int mf = 0; mf < 4; ++mf)
#pragma unroll
      for (int nf = 0; nf < 2; ++nf)
#pragma unroll
        for (int j = 0; j < 4; ++j){
          const int q = wr * 64 + mf * 16 + (lane >> 4) * 4 + j;
          const int b = b0 + wc * 32 + nf * 16 + (lane & 15);
          OUTF[(size_t)q * 8192 + b] = acc[mf][nf][j];
        }
  } else {
#pragma unroll
    for (int mf = 0; mf < 4; ++mf)
#pragma unroll
      for (int nf = 0; nf < 2; ++nf){
        const int rBase = wr * 64 + mf * 16 + (lane >> 4) * 4;
        const int bL = wc * 32 + nf * 16 + (lane & 15);
        bf4 p;
#pragma unroll
        for (int j = 0; j < 4; ++j) p[j] = (short)f2bf(acc[mf][nf][j]);
        *(bf4*)(lds + ((bL * 256 + rBase * 2) ^ ((bL & 7) << 4))) = p;
      }
    __syncthreads();
#pragma unroll
    for (int u = 0; u < 4; ++u){
      const int sIdx = u * 256 + tid;
      const int bL = sIdx >> 4, slot = sIdx & 15;
      bf8 v = *(const bf8*)(lds + bL * 256 + ((slot ^ (bL & 7)) << 4));
      *(bf8*)(OUTT + (size_t)(b0 + bL) * 128 + slot * 8) = v;
    }
  }
}

// ---------------- core: LDS-ring GEMM, counted vmcnt, split-K(q)=4 ----------------
// Block 128p x 128b, 8 waves (4x2), wave = 32p x 64b.
// LDS: A ring 4 x 32KB ([128p][128r] bf16 per q, swizzled) + x1 slice 16KB.
__global__ __launch_bounds__(512, 2) void k_core(const unsigned short* __restrict__ Gbf,  // [128][16384]
                                                 const float* __restrict__ UX1,           // [128][8192]
                                                 const unsigned short* __restrict__ UX2T, // [8192][128]
                                                 unsigned short* __restrict__ PT){        // [4][8192][128] bf16
  __shared__ __align__(16) unsigned char lds[147456];      // ring 128K + x1 16K
  unsigned char* ldsX = lds + 131072;
  const int tid = threadIdx.x, lane = tid & 63, wv = tid >> 6;
  const int g = lane >> 4, l15 = lane & 15;
  const int wr = wv >> 1, wc = wv & 1;        // 4 x 2 waves; wave tile 32p x 64b
  // XCD-aware: round-robin dispatch => xcd = blk & 7; 2 XCDs per split.
  const int blk = blockIdx.x;                 // 0..255
  const int xcd = blk & 7, slot = blk >> 3;   // slot 0..31
  const int split = xcd >> 1;                 // 0..3
  const int b0 = ((xcd & 1) * 32 + slot) * 128;
  const int q0 = split * 32;

  auto stageA = [&](int q, int buf){
#pragma unroll
    for (int rnd = 0; rnd < 4; ++rnd){
      const int off = rnd * 8192 + wv * 1024 + lane * 16;  // 0..32767
      const int row = off >> 8;                            // p-row 0..127
      const int ss = ((off >> 4) & 15) ^ (row & 7);        // source pre-swizzle
      glds16(Gbf + (size_t)row * 16384 + (size_t)q * 128 + ss * 8,
             lds + buf * 32768 + off);
    }
  };

  // prologue: x1 slice [32q][128b] f32 -> ldsX (2 glds, oldest in vmcnt queue)
#pragma unroll
  for (int rnd = 0; rnd < 2; ++rnd){
    const int off = rnd * 8192 + wv * 1024 + lane * 16;
    const int row = off >> 9;                              // q-row 0..31
    glds16(UX1 + (size_t)(q0 + row) * 8192 + b0 + ((off >> 2) & 127), ldsX + off);
  }
  // B hoist: 16 bf8 = 64 VGPR, for whole kernel (normal loads, compiler-tracked)
  bf8 Bf[4][4];
#pragma unroll
  for (int kc = 0; kc < 4; ++kc)
#pragma unroll
    for (int nf = 0; nf < 4; ++nf)
      Bf[kc][nf] = *(const bf8*)(UX2T + (size_t)(b0 + wc * 64 + nf * 16 + l15) * 128 +
                                 kc * 32 + g * 8);
  stageA(q0 + 0, 0);
  stageA(q0 + 1, 1);
  stageA(q0 + 2, 2);

  f4 acc[2][4];
#pragma unroll
  for (int mf = 0; mf < 2; ++mf)
#pragma unroll
    for (int nf = 0; nf < 4; ++nf) acc[mf][nf] = (f4){0.f, 0.f, 0.f, 0.f};

  auto bodyq = [&](int i){
    const unsigned char* A = lds + (i & 3) * 32768;
    float xs[4];
#pragma unroll
    for (int nf = 0; nf < 4; ++nf)
      xs[nf] = *(const float*)(ldsX + i * 512 + (wc * 64 + nf * 16 + l15) * 4);
    bf8 a[2][4];
#pragma unroll
    for (int mf = 0; mf < 2; ++mf){
      const int row = wr * 32 + mf * 16 + l15;
#pragma unroll
      for (int kc = 0; kc < 4; ++kc)
        a[mf][kc] = *(const bf8*)(A + row * 256 + ((((kc << 2) + g) ^ (row & 7)) << 4));
    }
#pragma unroll
    for (int mf = 0; mf < 2; ++mf)
#pragma unroll
      for (int nf = 0; nf < 4; ++nf){
        f4 y = __builtin_amdgcn_mfma_f32_16x16x32_bf16(a[mf][0], Bf[0][nf], (f4){0.f,0.f,0.f,0.f}, 0, 0, 0);
        y = __builtin_amdgcn_mfma_f32_16x16x32_bf16(a[mf][1], Bf[1][nf], y, 0, 0, 0);
        y = __builtin_amdgcn_mfma_f32_16x16x32_bf16(a[mf][2], Bf[2][nf], y, 0, 0, 0);
        y = __builtin_amdgcn_mfma_f32_16x16x32_bf16(a[mf][3], Bf[3][nf], y, 0, 0, 0);
        acc[mf][nf] += y * xs[nf];                        // fold x1 in f32
      }
  };

  // main loop: counted vmcnt keeps 2 stages in flight across the barrier
  for (int i = 0; i < 30; ++i){
    asm volatile("s_waitcnt vmcnt(8)" ::: "memory");      // stage(i) landed
    __builtin_amdgcn_s_barrier();
    stageA(q0 + i + 3, (i + 3) & 3);                      // issue-early (T14)
    bodyq(i);
  }
  asm volatile("s_waitcnt vmcnt(4)" ::: "memory");
  __builtin_amdgcn_s_barrier();
  bodyq(30);
  asm volatile("s_waitcnt vmcnt(0)" ::: "memory");
  __builtin_amdgcn_s_barrier();
  bodyq(31);

  // epilogue: acc -> PT[split][b][p] bf16 via swizzled LDS transpose (64KB f32)
  __syncthreads();
#pragma unroll
  for (int mf = 0; mf < 2; ++mf)
#pragma unroll
    for (int nf = 0; nf < 4; ++nf){
      const int bL = wc * 64 + nf * 16 + l15;             // 0..127
      const int pq = wr * 8 + mf * 4 + g;                 // p-quad 0..31
      *(f4*)(lds + bL * 512 + ((pq ^ (bL & 7)) << 4)) = acc[mf][nf];
    }
  __syncthreads();
#pragma unroll
  for (int rnd = 0; rnd < 4; ++rnd){
    const int idx = rnd * 512 + tid;                      // 2048 bf8 chunks
    const int bL = idx >> 4, s8 = idx & 15;
    f4 lo = *(const f4*)(lds + bL * 512 + (((s8 * 2) ^ (bL & 7)) << 4));
    f4 hi = *(const f4*)(lds + bL * 512 + (((s8 * 2 + 1) ^ (bL & 7)) << 4));
    bf8 o;
#pragma unroll
    for (int j = 0; j < 4; ++j){
      o[j] = (short)f2bf(lo[j]);
      o[4 + j] = (short)f2bf(hi[j]);
    }
    *(bf8*)(PT + (size_t)split * 1048576 + (size_t)(b0 + bL) * 128 + s8 * 8) = o;
  }
}

// ---------------- reduce split-K bf16 partials -> coreT bf16 [8192][128] ----------------
__global__ __launch_bounds__(256) void k_red(const unsigned short* __restrict__ PT,
                                             unsigned short* __restrict__ coreT){
  const int c = blockIdx.x * 256 + threadIdx.x;           // 0..131071 bf8 chunks
  const bf8* P = (const bf8*)PT;
  bf8 v0 = P[c], v1 = P[c + 131072], v2 = P[c + 262144], v3 = P[c + 393216];
  bf8 o;
#pragma unroll
  for (int j = 0; j < 8; ++j){
    float s = bf2f((unsigned short)v0[j]) + bf2f((unsigned short)v1[j]) +
              bf2f((unsigned short)v2[j]) + bf2f((unsigned short)v3[j]);
    o[j] = (short)f2bf(s);
  }
  ((bf8*)coreT)[c] = o;
}

// ---------------- Z = U0 @ core: M=512, N=8192, K=128 ----------------
__global__ __launch_bounds__(256) void k_z(const unsigned short* __restrict__ U0bf,  // [512][128]
                                           const unsigned short* __restrict__ coreT, // [8192][128]
                                           float* __restrict__ Z){                   // [512][8192]
  __shared__ __align__(16) unsigned char lds[32768];
  unsigned char* ldsA = lds;
  unsigned char* ldsB = lds + 16384;
  const int tid = threadIdx.x, lane = tid & 63, wv = tid >> 6;
  const int wr = wv >> 1, wc = wv & 1;
  const int b0 = blockIdx.x * 128;
  const int d0 = blockIdx.y * 128;
  f4 acc[4][4] = {};

#pragma unroll
  for (int it = 0; it < 2; ++it){
    const int k0 = it * 64;
#pragma unroll
    for (int i = 0; i < 4; ++i){
      const int L = (wv * 4 + i) * 1024 + lane * 16;
      const int row = L >> 7;
      const int ss = (lane & 7) ^ (row & 7);
      glds16(U0bf + (size_t)(d0 + row) * 128 + k0 + ss * 8, ldsA + (wv * 4 + i) * 1024);
      glds16(coreT + (size_t)(b0 + row) * 128 + k0 + ss * 8, ldsB + (wv * 4 + i) * 1024);
    }
    __syncthreads();
#pragma unroll
    for (int kc = 0; kc < 2; ++kc){
      const int g = lane >> 4;
      bf8 a[4], b[4];
#pragma unroll
      for (int mf = 0; mf < 4; ++mf){
        const int r = wr * 64 + mf * 16 + (lane & 15);
        a[mf] = *(const bf8*)(ldsA + r * 128 + (((kc * 4 + g) ^ (r & 7)) << 4));
      }
#pragma unroll
      for (int nf = 0; nf < 4; ++nf){
        const int rb = wc * 64 + nf * 16 + (lane & 15);
        b[nf] = *(const bf8*)(ldsB + rb * 128 + (((kc * 4 + g) ^ (rb & 7)) << 4));
      }
#pragma unroll
      for (int mf = 0; mf < 4; ++mf)
#pragma unroll
        for (int nf = 0; nf < 4; ++nf)
          acc[mf][nf] = __builtin_amdgcn_mfma_f32_16x16x32_bf16(a[mf], b[nf], acc[mf][nf], 0, 0, 0);
    }
    __syncthreads();
  }
#pragma unroll
  for (int mf = 0; mf < 4; ++mf)
#pragma unroll
    for (int nf = 0; nf < 4; ++nf)
#pragma unroll
      for (int j = 0; j < 4; ++j){
        const int d = d0 + wr * 64 + mf * 16 + (lane >> 4) * 4 + j;
        const int b = b0 + wc * 64 + nf * 16 + (lane & 15);
        Z[(size_t)d * 8192 + b] = acc[mf][nf][j];
      }
}

// ---------------- host launch ----------------
extern "C" void kernel_launch(void* const* d_in, const int* in_sizes, int n_in,
                              void* d_out, int out_size, void* d_ws, size_t ws_size,
                              hipStream_t stream){
  const float* X1 = (const float*)d_in[0];
  const float* X2 = (const float*)d_in[1];
  const float* U0 = (const float*)d_in[2];
  const float* U1 = (const float*)d_in[3];
  const float* U2 = (const float*)d_in[4];
  const float* G  = (const float*)d_in[5];
  float* Z = (float*)d_out;

  char* ws = (char*)d_ws;
  unsigned short* Gbf   = (unsigned short*)(ws);              //  4,194,304 B
  unsigned short* U0bf  = (unsigned short*)(ws + 4194304);    //    131,072 B
  unsigned short* U1T   = (unsigned short*)(ws + 4325376);    //    131,072 B
  unsigned short* U2T   = (unsigned short*)(ws + 4456448);    //    131,072 B
  float*          UX1   = (float*)         (ws + 4587520);    //  4,194,304 B
  unsigned short* UX2T  = (unsigned short*)(ws + 8781824);    //  2,097,152 B
  unsigned short* coreT = (unsigned short*)(ws + 10878976);   //  2,097,152 B
  unsigned short* PT    = (unsigned short*)(ws + 12976128);   //  8,388,608 B (bf16 x4 splits)

  k_cast<<<dim3(2624), dim3(256), 0, stream>>>(G, U0, U1, U2, Gbf, U0bf, U1T, U2T);
  k_ux2 <<<dim3(128, 2), dim3(256), 0, stream>>>(U1T, U2T, X1, X2, UX1, UX2T);
  k_core<<<dim3(256), dim3(512), 0, stream>>>(Gbf, UX1, UX2T, PT);
  k_red <<<dim3(512), dim3(256), 0, stream>>>(PT, coreT);
  k_z   <<<dim3(64, 4), dim3(256), 0, stream>>>(U0bf, coreT, Z);
}